// Round 4
// baseline (271.993 us; speedup 1.0000x reference)
//
#include <hip/hip_runtime.h>

// WaveletParsingLayer: per-row stable stream compaction.
// x3[B,C,L] -> out[B,C,KEEP], dropping elements == FILLER (10.1f), order-preserving.
// x1, x2 are unused by the reference.
//
// R8 == R7 resubmitted (R7 bench died on GPUAcquisitionTimeout; kernel never ran).
//
// R7 rationale: R6's two-row register pipeline spilled (launch_bounds VGPR
// cap 85 vs ~80+ regs of payload -> +72MB scratch traffic, 79->90us). New
// structure: stage 16-bit SOURCE INDICES in LDS instead of f32 values.
//  - per-chunk state packs to one int (4 survivor bits | prefix<<4) -> no
//    payload registers, no spill possible;
//  - LDS stage halves to 24KB -> 6 blocks/CU (24 waves, 75% occ), six
//    independent blocks interleave load/scatter/store phases -> fixes the
//    burst-idle-burst HBM duty cycle (R5: 26.5% BW, nothing saturated);
//  - copy-out gathers values from the row via L2 (row is L2-hot, fetched by
//    this CU moments earlier; gather addresses monotone -> coalescer-friendly),
//    output stores remain perfectly coalesced float4.

#define FILLER_VAL 10.1f
constexpr int L_LEN    = 16384;
constexpr int KEEP_LEN = 12288;
constexpr int BLOCK    = 256;           // 4 waves of 64
constexpr int NW       = BLOCK / 64;    // waves per block = 4
constexpr int CHUNK    = BLOCK * 4;     // 1024 elements per chunk
constexpr int NC       = L_LEN / CHUNK; // 16 chunks per row

__global__ __launch_bounds__(BLOCK, 6) void compact_rows_kernel(
    const float* __restrict__ x3, float* __restrict__ out)
{
    const int row = blockIdx.x;
    const float* __restrict__ in = x3 + (size_t)row * L_LEN;
    float* __restrict__ o = out + (size_t)row * KEEP_LEN;

    const int tid  = threadIdx.x;
    const int lane = tid & 63;
    const int wid  = tid >> 6;
    const unsigned long long lt = (1ULL << lane) - 1ULL;

    __shared__ unsigned short stage[KEEP_LEN];  // 24 KB survivor source-index staging
    __shared__ int wtot[NC][NW];                // per-chunk per-wave survivor counts

    // ---- Phase A: load row, ballot, pack per-chunk state, discard values.
    // pk[c] = survivor bits (4) | exclusive-prefix-within-wave (<<4).
    int pk[NC];
    #pragma unroll
    for (int c = 0; c < NC; ++c) {
        const float4 v = *reinterpret_cast<const float4*>(in + c * CHUNK + tid * 4);
        const unsigned long long m0 = __ballot(v.x != FILLER_VAL);
        const unsigned long long m1 = __ballot(v.y != FILLER_VAL);
        const unsigned long long m2 = __ballot(v.z != FILLER_VAL);
        const unsigned long long m3 = __ballot(v.w != FILLER_VAL);
        const int before = __popcll(m0 & lt) + __popcll(m1 & lt)
                         + __popcll(m2 & lt) + __popcll(m3 & lt);
        const int bits = (int)((m0 >> lane) & 1ULL)
                       | ((int)((m1 >> lane) & 1ULL) << 1)
                       | ((int)((m2 >> lane) & 1ULL) << 2)
                       | ((int)((m3 >> lane) & 1ULL) << 3);
        pk[c] = bits | (before << 4);
        if (lane == 0)
            wtot[c][wid] = __popcll(m0) + __popcll(m1)
                         + __popcll(m2) + __popcll(m3);
    }
    __syncthreads();   // barrier 1: wtot visible

    // ---- Phase B: prefix over (chunk, wave) + scatter u16 source indices.
    int run = 0;
    #pragma unroll
    for (int c = 0; c < NC; ++c) {
        int wb = run;
        #pragma unroll
        for (int w = 0; w < NW; ++w) {
            const int t = wtot[c][w];
            if (w < wid) wb += t;
            run += t;
        }
        const int bits   = pk[c] & 15;
        const int before = pk[c] >> 4;
        const int p0 = wb + before;
        const int p1 = p0 + (bits & 1);
        const int p2 = p1 + ((bits >> 1) & 1);
        const int p3 = p2 + ((bits >> 2) & 1);
        const int idx = c * CHUNK + tid * 4;
        if ((bits & 1) && p0 < KEEP_LEN) stage[p0] = (unsigned short)(idx);
        if ((bits & 2) && p1 < KEEP_LEN) stage[p1] = (unsigned short)(idx + 1);
        if ((bits & 4) && p2 < KEEP_LEN) stage[p2] = (unsigned short)(idx + 2);
        if ((bits & 8) && p3 < KEEP_LEN) stage[p3] = (unsigned short)(idx + 3);
    }
    __syncthreads();   // barrier 2: stage complete

    // ---- Phase C: gather via L2-hot row + coalesced float4 stores.
    // 12288 outputs = 6 iters x (2 x ushort4 LDS read, 8 gathers, 2 float4 stores).
    #pragma unroll
    for (int it = 0; it < KEEP_LEN / (BLOCK * 8); ++it) {
        const int o0 = it * (BLOCK * 8) + tid * 4;           // first 4-output slot
        const int o1 = o0 + BLOCK * 4;                       // second 4-output slot
        const ushort4 i0 = *reinterpret_cast<const ushort4*>(&stage[o0]);
        const ushort4 i1 = *reinterpret_cast<const ushort4*>(&stage[o1]);
        float4 a, b;
        a.x = in[i0.x]; a.y = in[i0.y]; a.z = in[i0.z]; a.w = in[i0.w];
        b.x = in[i1.x]; b.y = in[i1.y]; b.z = in[i1.z]; b.w = in[i1.w];
        *reinterpret_cast<float4*>(&o[o0]) = a;
        *reinterpret_cast<float4*>(&o[o1]) = b;
    }
}

extern "C" void kernel_launch(void* const* d_in, const int* in_sizes, int n_in,
                              void* d_out, int out_size, void* d_ws, size_t ws_size,
                              hipStream_t stream)
{
    // in order: x1 [B,C,4096] f32 (unused), x2 [B,C,4096] f32 (unused),
    //           x3 [B,C,L] f32, keep_len (scalar int, value 12288)
    const float* x3 = (const float*)d_in[2];
    float* out = (float*)d_out;

    const int rows = in_sizes[2] / L_LEN;  // B*C = 2048

    compact_rows_kernel<<<rows, BLOCK, 0, stream>>>(x3, out);
}

// Round 5
// 255.933 us; speedup vs baseline: 1.0628x; 1.0628x over previous
//
#include <hip/hip_runtime.h>

// WaveletParsingLayer: per-row stable stream compaction.
// x3[B,C,L] -> out[B,C,KEEP], dropping elements == FILLER (10.1f), order-preserving.
// x1, x2 are unused by the reference.
//
// R9: ledger: R4 value-stage <=78us | R5 79us | R6 2-row reg pipeline 90us
// (spilled) | R8 u16-index stage + L2 gather 89us (FETCH +60MB, gather
// latency-serialized). All compiled to VGPR=40 because every version set
// __launch_bounds__(...,6). But the 48KB-stage design is LDS-capped at
// 3 blocks/CU (= 3 waves/SIMD) anyway -> correct VGPR budget is 512/3=170.
// At 40 VGPRs the load phase can't hold 16 float4 in flight -> serial
// ~900cy latency rounds -> all pipes idle (HBM 26-32%, VALU 14-17%).
// Fix: launch_bounds(256,3); load ALL 16 float4 before balloting (full-MLP
// 64KB burst per block); 2 rows/block so row1's load burst overlaps row0's
// copyout stores. Guard metric: WRITE_SIZE must stay 98304 KB (no spill).

#define FILLER_VAL 10.1f
constexpr int L_LEN    = 16384;
constexpr int KEEP_LEN = 12288;
constexpr int BLOCK    = 256;           // 4 waves of 64
constexpr int NW       = BLOCK / 64;    // waves per block = 4
constexpr int CHUNK    = BLOCK * 4;     // 1024 elements per chunk
constexpr int NC       = L_LEN / CHUNK; // 16 chunks per row
constexpr int RPB      = 2;             // rows per block (sequential, pipelined)

__global__ __launch_bounds__(BLOCK, 3) void compact_rows_kernel(
    const float* __restrict__ x3, float* __restrict__ out, int rows)
{
    const int tid  = threadIdx.x;
    const int lane = tid & 63;
    const int wid  = tid >> 6;
    const unsigned long long lt = (1ULL << lane) - 1ULL;

    __shared__ float stage[KEEP_LEN];   // 48 KB survivor value staging
    __shared__ int wtot[NC][NW];        // per-chunk per-wave survivor counts

    #pragma unroll
    for (int r = 0; r < RPB; ++r) {
        const int row = blockIdx.x * RPB + r;   // block-uniform
        if (row >= rows) break;
        const float* __restrict__ in = x3 + (size_t)row * L_LEN;
        float* __restrict__ o = out + (size_t)row * KEEP_LEN;

        // ---- Phase A1: issue ALL 16 row loads back-to-back (full MLP).
        // For r=1 these overlap r=0's copyout global stores.
        float4 v[NC];
        #pragma unroll
        for (int c = 0; c < NC; ++c)
            v[c] = *reinterpret_cast<const float4*>(in + c * CHUNK + tid * 4);

        // ---- Phase A2: ballots; pack per-chunk state (bits | before<<4).
        int pk[NC];
        #pragma unroll
        for (int c = 0; c < NC; ++c) {
            const unsigned long long m0 = __ballot(v[c].x != FILLER_VAL);
            const unsigned long long m1 = __ballot(v[c].y != FILLER_VAL);
            const unsigned long long m2 = __ballot(v[c].z != FILLER_VAL);
            const unsigned long long m3 = __ballot(v[c].w != FILLER_VAL);
            const int before = __popcll(m0 & lt) + __popcll(m1 & lt)
                             + __popcll(m2 & lt) + __popcll(m3 & lt);
            const int bits = (int)((m0 >> lane) & 1ULL)
                           | ((int)((m1 >> lane) & 1ULL) << 1)
                           | ((int)((m2 >> lane) & 1ULL) << 2)
                           | ((int)((m3 >> lane) & 1ULL) << 3);
            pk[c] = bits | (before << 4);
            if (lane == 0)
                wtot[c][wid] = __popcll(m0) + __popcll(m1)
                             + __popcll(m2) + __popcll(m3);
        }
        // barrier 1: wtot visible; also guarantees previous row's copyout
        // LDS reads are complete before this row's scatter reuses stage.
        __syncthreads();

        // ---- Phase B: prefix over (chunk, wave) + scatter values into LDS.
        int run = 0;
        #pragma unroll
        for (int c = 0; c < NC; ++c) {
            int wb = run;
            #pragma unroll
            for (int w = 0; w < NW; ++w) {
                const int t = wtot[c][w];
                if (w < wid) wb += t;
                run += t;
            }
            const int bits   = pk[c] & 15;
            const int before = pk[c] >> 4;
            const int p0 = wb + before;
            const int p1 = p0 + (bits & 1);
            const int p2 = p1 + ((bits >> 1) & 1);
            const int p3 = p2 + ((bits >> 2) & 1);
            if ((bits & 1) && p0 < KEEP_LEN) stage[p0] = v[c].x;
            if ((bits & 2) && p1 < KEEP_LEN) stage[p1] = v[c].y;
            if ((bits & 4) && p2 < KEEP_LEN) stage[p2] = v[c].z;
            if ((bits & 8) && p3 < KEEP_LEN) stage[p3] = v[c].w;
        }
        __syncthreads();   // barrier 2: stage complete

        // ---- Phase C: coalesced copy-out, 12 float4 per thread.
        #pragma unroll
        for (int k = 0; k < KEEP_LEN / (BLOCK * 4); ++k) {
            const int idx = (k * BLOCK + tid) * 4;
            *reinterpret_cast<float4*>(&o[idx]) =
                *reinterpret_cast<const float4*>(&stage[idx]);
        }
    }
}

extern "C" void kernel_launch(void* const* d_in, const int* in_sizes, int n_in,
                              void* d_out, int out_size, void* d_ws, size_t ws_size,
                              hipStream_t stream)
{
    // in order: x1 [B,C,4096] f32 (unused), x2 [B,C,4096] f32 (unused),
    //           x3 [B,C,L] f32, keep_len (scalar int, value 12288)
    const float* x3 = (const float*)d_in[2];
    float* out = (float*)d_out;

    const int rows = in_sizes[2] / L_LEN;       // B*C = 2048
    const int grid = (rows + RPB - 1) / RPB;    // 1024

    compact_rows_kernel<<<grid, BLOCK, 0, stream>>>(x3, out, rows);
}